// Round 1
// baseline (891.362 us; speedup 1.0000x reference)
//
#include <hip/hip_runtime.h>

#define HDIM   64
#define TSTEPS 5
#define WAVES  16
#define BLOCK  (WAVES * 64)     // 1024 threads
#define EPW    16               // batch per wave = MFMA M
#define EPB    (WAVES * EPW)    // 256 batch per block

typedef _Float16 f16x8 __attribute__((ext_vector_type(8)));
typedef float    f32x4 __attribute__((ext_vector_type(4)));

#define L2E 1.44269504088896340736f   // log2(e)

// Native 1-ulp ops (trans pipe, quarter rate -> minimize count)
__device__ __forceinline__ float rcp_(float x) { return __builtin_amdgcn_rcpf(x); }
__device__ __forceinline__ float ex2_(float x) { return __builtin_amdgcn_exp2f(x); }

// Gates as D[m=batch e][n=gate row j'] = A[e][k] * B[k][j'] + C(bias + x*W_ih)
// A = h^T (per-timestep, rebuilt), B = W_hh^T (staged once, PRE-SCALED by
// log2e for i/f/o columns and 2*log2e for g columns so activations use raw
// v_exp_f32 = 2^x with no multiply).
// 16x16x32 f16 layouts (verified earlier, absmax 9.8e-4):
//   A-frag: lane holds A[m=lane&15][k = kh*32 + (lane>>4)*8 + i], i=0..7
//   B-frag: lane holds B[k = kh*32 + (lane>>4)*8 + i][n = ntile*16 + (lane&15)]
//   C/D:    lane holds D[m = (lane>>4)*4 + reg][n = ntile*16 + (lane&15)]
//
// Activation algebra (common-denominator form; saves 3 rcp per u):
//   Ei=2^-vi Ef=2^-vf Eg=2^vg Eo=2^-vo  (v pre-scaled by log2e / 2log2e)
//   cs' = [cs*Di*(Eg+1) + 2L2E*Df*(Eg-1)] / [Df*Di*(Eg+1)]    (1 rcp)
//   h   = (Ec-1) / [Do*(Ec+1)],  Ec = 2^cs'                    (1 rcp)
// -> 5 ex2 + 2 rcp per hidden unit (was 5 ex2 + 5 rcp).
__global__ __launch_bounds__(BLOCK, 8) void lstm_mfma_kernel(
    const float* __restrict__ x,      // [B, T, 1]
    const float* __restrict__ W_ih,   // [256, 1]
    const float* __restrict__ W_hh,   // [256, 64]
    const float* __restrict__ b_ih,   // [256]
    const float* __restrict__ b_hh,   // [256]
    const float* __restrict__ W_fc,   // [1, 64]
    const float* __restrict__ b_fc,   // [1]
    float* __restrict__ out,          // [B, 1]
    int B)
{
    __shared__ _Float16 Wf[2048 * 8];          // 32 KB, B-fragments, fragment-linear
    __shared__ _Float16 hbuf[WAVES * 1024];    // 32 KB, per-wave h A-fragments
    __shared__ float    wih_s[256];            // 1 KB (pre-scaled)
    __shared__ float    cb_s[256];             // 1 KB (pre-scaled b_ih + b_hh)

    const int tid = threadIdx.x;

    // ---- one-time staging: W_hh -> fp16 B-fragments, log2e pre-scaled ----
    #pragma unroll
    for (int s0 = 0; s0 < 2048; s0 += BLOCK) {
        const int s  = s0 + tid;
        const int ln = s & 63;
        const int kh = (s >> 6) & 1;
        const int n  = s >> 7;                             // N-tile 0..15, gate G = n>>2
        const float scl = ((n >> 2) == 2) ? (2.0f * L2E) : L2E;
        const int j  = n * 16 + (ln & 15);                 // gate row j'
        const int k0 = kh * 32 + ((ln >> 4) & 3) * 8;      // hidden k
        const float* src = W_hh + j * HDIM + k0;
        #pragma unroll
        for (int i = 0; i < 8; i++)
            Wf[s * 8 + i] = (_Float16)(src[i] * scl);
    }
    if (tid < 256) {
        const float scl = ((tid >> 6) == 2) ? (2.0f * L2E) : L2E;
        wih_s[tid] = W_ih[tid] * scl;
        cb_s[tid]  = (b_ih[tid] + b_hh[tid]) * scl;
    }
    __syncthreads();   // only barrier in the kernel

    const int lane = tid & 63;
    const int wave = tid >> 6;
    const int m    = lane & 15;    // C-layout column (gate-row local) / A row m
    const int q    = lane >> 4;    // quad
    const int eg0  = (blockIdx.x * WAVES + wave) * EPW;

    _Float16* hb = hbuf + wave * 1024;

    // x base pointers for this lane's 4 batch rows (hoisted; per-t load is imm offset)
    const float* xp[4];
    #pragma unroll
    for (int r = 0; r < 4; r++) {
        int e = eg0 + q * 4 + r;
        if (e >= B) e = B - 1;
        xp[r] = x + (long)e * TSTEPS;
    }

    float c[16];    // cell state, SCALED by 2*log2e; [gr*4+r] <-> (j=gr*16+m, e=q*4+r)
    float hv[16];   // last hidden state (unscaled), same indexing

    for (int t = 0; t < TSTEPS; t++) {
        float xt[4];
        #pragma unroll
        for (int r = 0; r < 4; r++) xt[r] = xp[r][t];

        // h A-fragments from previous timestep (same-wave LDS, no barrier needed)
        f16x8 hA0, hA1;
        if (t > 0) {
            hA0 = *(const f16x8*)(hb + lane * 8);          // kh = 0
            hA1 = *(const f16x8*)(hb + 512 + lane * 8);    // kh = 1
        }

        #pragma unroll
        for (int gr = 0; gr < 4; gr++) {       // j' chunk: j = gr*16 + m
            // C-init: bias + x*W_ih directly as the MFMA C operand
            float wihv[4], cbv[4];
            #pragma unroll
            for (int G = 0; G < 4; G++) {
                wihv[G] = wih_s[G * 64 + gr * 16 + m];   // broadcast, conflict-free
                cbv[G]  = cb_s[G * 64 + gr * 16 + m];
            }
            f32x4 ag[4];
            #pragma unroll
            for (int G = 0; G < 4; G++)
                #pragma unroll
                for (int r = 0; r < 4; r++)
                    ag[G][r] = fmaf(xt[r], wihv[G], cbv[G]);

            if (t > 0) {
                #pragma unroll
                for (int G = 0; G < 4; G++) {
                    const int n = G * 4 + gr;
                    f16x8 w0 = *(const f16x8*)(Wf + (n * 2 + 0) * 512 + lane * 8);
                    f16x8 w1 = *(const f16x8*)(Wf + (n * 2 + 1) * 512 + lane * 8);
                    ag[G] = __builtin_amdgcn_mfma_f32_16x16x32_f16(hA0, w0, ag[G], 0, 0, 0);
                    ag[G] = __builtin_amdgcn_mfma_f32_16x16x32_f16(hA1, w1, ag[G], 0, 0, 0);
                }
            }

            #pragma unroll
            for (int r = 0; r < 4; r++) {
                const int u = gr * 4 + r;
                // 5 ex2 + 2 rcp (t>0); 4 ex2 + 2 rcp (t==0)
                const float Ei = ex2_(-ag[0][r]);
                const float Eg = ex2_(ag[2][r]);
                const float Eo = ex2_(-ag[3][r]);
                const float Di = 1.0f + Ei;
                const float P  = Eg + 1.0f;
                const float M  = Eg - 1.0f;
                float num, den;
                if (t > 0) {
                    const float Ef = ex2_(-ag[1][r]);
                    const float Df = 1.0f + Ef;
                    num = fmaf(Df * M, 2.0f * L2E, (c[u] * Di) * P);
                    den = (Df * Di) * P;
                } else {
                    num = (2.0f * L2E) * M;
                    den = Di * P;
                }
                const float cs = num * rcp_(den);   // scaled domain (2*log2e*c)
                c[u] = cs;
                const float Ec = ex2_(cs);
                const float Do = 1.0f + Eo;
                const float hn = (Ec - 1.0f) * rcp_(Do * (Ec + 1.0f));
                hv[u] = hn;
                if (t < TSTEPS - 1) {
                    // scatter h (fp16) into next timestep's A-fragment slots
                    const int lp = (q * 4 + r) + 16 * (2 * (gr & 1) + (m >> 3));
                    hb[(gr >> 1) * 512 + lp * 8 + (m & 7)] = (_Float16)hn;
                }
            }
        }
    }

    // ---- FC epilogue: out[e] = sum_j h[j][e] * W_fc[j] + b_fc ----
    float wfc[4];
    #pragma unroll
    for (int n = 0; n < 4; n++) wfc[n] = W_fc[n * 16 + m];
    const float bfc = b_fc[0];

    #pragma unroll
    for (int r = 0; r < 4; r++) {
        float p = hv[r] * wfc[0];
        p = fmaf(hv[4 + r],  wfc[1], p);
        p = fmaf(hv[8 + r],  wfc[2], p);
        p = fmaf(hv[12 + r], wfc[3], p);
        p += __shfl_xor(p, 1, 64);
        p += __shfl_xor(p, 2, 64);
        p += __shfl_xor(p, 4, 64);
        p += __shfl_xor(p, 8, 64);
        if (m == 0) {
            const int e = eg0 + q * 4 + r;
            if (e < B) out[e] = p + bfc;
        }
    }
}

extern "C" void kernel_launch(void* const* d_in, const int* in_sizes, int n_in,
                              void* d_out, int out_size, void* d_ws, size_t ws_size,
                              hipStream_t stream) {
    const float* x    = (const float*)d_in[0];
    const float* W_ih = (const float*)d_in[1];
    const float* W_hh = (const float*)d_in[2];
    const float* b_ih = (const float*)d_in[3];
    const float* b_hh = (const float*)d_in[4];
    const float* W_fc = (const float*)d_in[5];
    const float* b_fc = (const float*)d_in[6];
    float* out = (float*)d_out;

    const int B = in_sizes[0] / TSTEPS;   // x is [B, T, 1]
    const int grid = (B + EPB - 1) / EPB;
    lstm_mfma_kernel<<<grid, BLOCK, 0, stream>>>(x, W_ih, W_hh, b_ih, b_hh,
                                                 W_fc, b_fc, out, B);
}

// Round 2
// 457.073 us; speedup vs baseline: 1.9502x; 1.9502x over previous
//
#include <hip/hip_runtime.h>

#define HDIM   64
#define TSTEPS 5
#define WAVES  8
#define BLOCK  (WAVES * 64)     // 512 threads
#define EPW    16               // batch per wave = MFMA M
#define EPB    (WAVES * EPW)    // 128 batch per block

typedef _Float16 f16x8 __attribute__((ext_vector_type(8)));
typedef float    f32x4 __attribute__((ext_vector_type(4)));

#define L2E 1.44269504088896340736f   // log2(e)

// Native 1-ulp ops (trans pipe, quarter rate -> minimize count)
__device__ __forceinline__ float rcp_(float x) { return __builtin_amdgcn_rcpf(x); }
__device__ __forceinline__ float ex2_(float x) { return __builtin_amdgcn_exp2f(x); }

// Gates as D[m=batch e][n=gate row j'] = A[e][k] * B[k][j'] + C(bias + x*W_ih)
// A = h^T (per-timestep, rebuilt), B = W_hh^T (staged once, PRE-SCALED by
// log2e for i/f/o columns and 2*log2e for g columns so activations use raw
// v_exp_f32 = 2^x with no multiply).
// 16x16x32 f16 layouts (verified, absmax 9.8e-4):
//   A-frag: lane holds A[m=lane&15][k = kh*32 + (lane>>4)*8 + i], i=0..7
//   B-frag: lane holds B[k = kh*32 + (lane>>4)*8 + i][n = ntile*16 + (lane&15)]
//   C/D:    lane holds D[m = (lane>>4)*4 + reg][n = ntile*16 + (lane&15)]
//
// Activation algebra (common-denominator form; saves 3 rcp per u):
//   Ei=2^-vi Ef=2^-vf Eg=2^vg Eo=2^-vo  (v pre-scaled by log2e / 2log2e)
//   cs' = [cs*Di*(Eg+1) + 2L2E*Df*(Eg-1)] / [Df*Di*(Eg+1)]    (1 rcp)
//   h   = (Ec-1) / [Do*(Ec+1)],  Ec = 2^cs'                    (1 rcp)
// -> 5 ex2 + 2 rcp per hidden unit (was 5 ex2 + 5 rcp).
//
// NOTE on launch_bounds: (512, 4) is the proven no-spill config (60 VGPR).
// Round-1 lesson: requesting 8 waves/EU squeezed VGPRs to 32 -> full spill
// of c[16]/hv[16] -> 2.8 GB scratch traffic, 8x slower. Do not raise it.
__global__ __launch_bounds__(BLOCK, 4) void lstm_mfma_kernel(
    const float* __restrict__ x,      // [B, T, 1]
    const float* __restrict__ W_ih,   // [256, 1]
    const float* __restrict__ W_hh,   // [256, 64]
    const float* __restrict__ b_ih,   // [256]
    const float* __restrict__ b_hh,   // [256]
    const float* __restrict__ W_fc,   // [1, 64]
    const float* __restrict__ b_fc,   // [1]
    float* __restrict__ out,          // [B, 1]
    int B)
{
    __shared__ _Float16 Wf[2048 * 8];          // 32 KB, B-fragments, fragment-linear
    __shared__ _Float16 hbuf[WAVES * 1024];    // 16 KB, per-wave h A-fragments
    __shared__ float    wih_s[256];            // 1 KB (pre-scaled)
    __shared__ float    cb_s[256];             // 1 KB (pre-scaled b_ih + b_hh)

    const int tid = threadIdx.x;

    // ---- one-time staging: W_hh -> fp16 B-fragments, log2e pre-scaled ----
    #pragma unroll
    for (int s0 = 0; s0 < 2048; s0 += BLOCK) {
        const int s  = s0 + tid;
        const int ln = s & 63;
        const int kh = (s >> 6) & 1;
        const int n  = s >> 7;                             // N-tile 0..15, gate G = n>>2
        const float scl = ((n >> 2) == 2) ? (2.0f * L2E) : L2E;
        const int j  = n * 16 + (ln & 15);                 // gate row j'
        const int k0 = kh * 32 + ((ln >> 4) & 3) * 8;      // hidden k
        const float* src = W_hh + j * HDIM + k0;
        #pragma unroll
        for (int i = 0; i < 8; i++)
            Wf[s * 8 + i] = (_Float16)(src[i] * scl);
    }
    if (tid < 256) {
        const float scl = ((tid >> 6) == 2) ? (2.0f * L2E) : L2E;
        wih_s[tid] = W_ih[tid] * scl;
        cb_s[tid]  = (b_ih[tid] + b_hh[tid]) * scl;
    }
    __syncthreads();   // only barrier in the kernel

    const int lane = tid & 63;
    const int wave = tid >> 6;
    const int m    = lane & 15;    // C-layout column (gate-row local) / A row m
    const int q    = lane >> 4;    // quad
    const int eg0  = (blockIdx.x * WAVES + wave) * EPW;

    _Float16* hb = hbuf + wave * 1024;

    // x base pointers for this lane's 4 batch rows (hoisted; per-t load is imm offset)
    const float* xp[4];
    #pragma unroll
    for (int r = 0; r < 4; r++) {
        int e = eg0 + q * 4 + r;
        if (e >= B) e = B - 1;
        xp[r] = x + (long)e * TSTEPS;
    }

    float c[16];    // cell state, SCALED by 2*log2e; [gr*4+r] <-> (j=gr*16+m, e=q*4+r)
    float hv[16];   // last hidden state (unscaled), same indexing

    for (int t = 0; t < TSTEPS; t++) {
        float xt[4];
        #pragma unroll
        for (int r = 0; r < 4; r++) xt[r] = xp[r][t];

        // h A-fragments from previous timestep (same-wave LDS, no barrier needed)
        f16x8 hA0, hA1;
        if (t > 0) {
            hA0 = *(const f16x8*)(hb + lane * 8);          // kh = 0
            hA1 = *(const f16x8*)(hb + 512 + lane * 8);    // kh = 1
        }

        #pragma unroll
        for (int gr = 0; gr < 4; gr++) {       // j' chunk: j = gr*16 + m
            // C-init: bias + x*W_ih directly as the MFMA C operand
            float wihv[4], cbv[4];
            #pragma unroll
            for (int G = 0; G < 4; G++) {
                wihv[G] = wih_s[G * 64 + gr * 16 + m];   // broadcast, conflict-free
                cbv[G]  = cb_s[G * 64 + gr * 16 + m];
            }
            f32x4 ag[4];
            #pragma unroll
            for (int G = 0; G < 4; G++)
                #pragma unroll
                for (int r = 0; r < 4; r++)
                    ag[G][r] = fmaf(xt[r], wihv[G], cbv[G]);

            if (t > 0) {
                #pragma unroll
                for (int G = 0; G < 4; G++) {
                    const int n = G * 4 + gr;
                    f16x8 w0 = *(const f16x8*)(Wf + (n * 2 + 0) * 512 + lane * 8);
                    f16x8 w1 = *(const f16x8*)(Wf + (n * 2 + 1) * 512 + lane * 8);
                    ag[G] = __builtin_amdgcn_mfma_f32_16x16x32_f16(hA0, w0, ag[G], 0, 0, 0);
                    ag[G] = __builtin_amdgcn_mfma_f32_16x16x32_f16(hA1, w1, ag[G], 0, 0, 0);
                }
            }

            #pragma unroll
            for (int r = 0; r < 4; r++) {
                const int u = gr * 4 + r;
                // 5 ex2 + 2 rcp (t>0); 4 ex2 + 2 rcp (t==0)
                const float Ei = ex2_(-ag[0][r]);
                const float Eg = ex2_(ag[2][r]);
                const float Eo = ex2_(-ag[3][r]);
                const float Di = 1.0f + Ei;
                const float P  = Eg + 1.0f;
                const float M  = Eg - 1.0f;
                float num, den;
                if (t > 0) {
                    const float Ef = ex2_(-ag[1][r]);
                    const float Df = 1.0f + Ef;
                    num = fmaf(Df * M, 2.0f * L2E, (c[u] * Di) * P);
                    den = (Df * Di) * P;
                } else {
                    num = (2.0f * L2E) * M;
                    den = Di * P;
                }
                const float cs = num * rcp_(den);   // scaled domain (2*log2e*c)
                c[u] = cs;
                const float Ec = ex2_(cs);
                const float Do = 1.0f + Eo;
                const float hn = (Ec - 1.0f) * rcp_(Do * (Ec + 1.0f));
                hv[u] = hn;
                if (t < TSTEPS - 1) {
                    // scatter h (fp16) into next timestep's A-fragment slots
                    const int lp = (q * 4 + r) + 16 * (2 * (gr & 1) + (m >> 3));
                    hb[(gr >> 1) * 512 + lp * 8 + (m & 7)] = (_Float16)hn;
                }
            }
        }
    }

    // ---- FC epilogue: out[e] = sum_j h[j][e] * W_fc[j] + b_fc ----
    float wfc[4];
    #pragma unroll
    for (int n = 0; n < 4; n++) wfc[n] = W_fc[n * 16 + m];
    const float bfc = b_fc[0];

    #pragma unroll
    for (int r = 0; r < 4; r++) {
        float p = hv[r] * wfc[0];
        p = fmaf(hv[4 + r],  wfc[1], p);
        p = fmaf(hv[8 + r],  wfc[2], p);
        p = fmaf(hv[12 + r], wfc[3], p);
        p += __shfl_xor(p, 1, 64);
        p += __shfl_xor(p, 2, 64);
        p += __shfl_xor(p, 4, 64);
        p += __shfl_xor(p, 8, 64);
        if (m == 0) {
            const int e = eg0 + q * 4 + r;
            if (e < B) out[e] = p + bfc;
        }
    }
}

extern "C" void kernel_launch(void* const* d_in, const int* in_sizes, int n_in,
                              void* d_out, int out_size, void* d_ws, size_t ws_size,
                              hipStream_t stream) {
    const float* x    = (const float*)d_in[0];
    const float* W_ih = (const float*)d_in[1];
    const float* W_hh = (const float*)d_in[2];
    const float* b_ih = (const float*)d_in[3];
    const float* b_hh = (const float*)d_in[4];
    const float* W_fc = (const float*)d_in[5];
    const float* b_fc = (const float*)d_in[6];
    float* out = (float*)d_out;

    const int B = in_sizes[0] / TSTEPS;   // x is [B, T, 1]
    const int grid = (B + EPB - 1) / EPB;
    lstm_mfma_kernel<<<grid, BLOCK, 0, stream>>>(x, W_ih, W_hh, b_ih, b_hh,
                                                 W_fc, b_fc, out, B);
}

// Round 3
// 401.874 us; speedup vs baseline: 2.2180x; 1.1374x over previous
//
#include <hip/hip_runtime.h>

#define HDIM   64
#define TSTEPS 5
#define WAVES  8
#define BLOCK  (WAVES * 64)     // 512 threads
#define EPW    16               // batch per wave = MFMA M
#define EPB    (WAVES * EPW)    // 128 batch per block

typedef _Float16 f16x8 __attribute__((ext_vector_type(8)));
typedef float    f32x4 __attribute__((ext_vector_type(4)));

#define L2E 1.44269504088896340736f   // log2(e)

// Native 1-ulp ops (trans pipe, quarter rate -> minimize count)
__device__ __forceinline__ float rcp_(float x) { return __builtin_amdgcn_rcpf(x); }
__device__ __forceinline__ float ex2_(float x) { return __builtin_amdgcn_exp2f(x); }

// Gates as D[m=batch e][n=gate row j'] = A[e][k] * B[k][j'] + C(bias + x*W_ih)
// A = h^T (per-timestep, rebuilt), B = W_hh^T (staged once, PRE-SCALED by
// log2e for i/f/o columns and 2*log2e for g columns so activations use raw
// v_exp_f32 = 2^x with no multiply).
// 16x16x32 f16 layouts (verified, absmax 9.8e-4):
//   A-frag: lane holds A[m=lane&15][k = kh*32 + (lane>>4)*8 + i], i=0..7
//   B-frag: lane holds B[k = kh*32 + (lane>>4)*8 + i][n = ntile*16 + (lane&15)]
//   C/D:    lane holds D[m = (lane>>4)*4 + reg][n = ntile*16 + (lane&15)]
//
// Activation: LOCAL fusions only (round-2 lesson: the global common-denominator
// form made live ranges long enough that the allocator spilled ~1.7 GB of
// scratch despite headroom; keep every temp consumed within 2-3 ops).
//   it = i*tanh(g)*2L2E = 2L2E*(Eg-1) * rcp((1+Ei)*(Eg+1))   (1 rcp, was 2)
//   sf = rcp(1+Ef)                                            (unchanged)
//   cs = fmaf(sf, c, it)          [c in 2L2E-scaled domain]
//   hn = o*tanh(c) = (Ec-1) * rcp((1+Eo)*(Ec+1))             (1 rcp, was 2)
// -> 5 ex2 + 3 rcp per hidden unit (was 5 ex2 + 5 rcp).
// t=0 peeled: c_prev=0 -> no f-gate, no MFMA, branch-free unrolled t=1..4.
//
// NOTE on launch_bounds: (512, 4) is the proven no-spill config.
// Round-1 lesson: requesting 8 waves/EU squeezed VGPRs to 32 -> full spill
// of c[16]/hv[16] -> 2.8 GB scratch traffic, 8x slower. Do not raise it.
__global__ __launch_bounds__(BLOCK, 4) void lstm_mfma_kernel(
    const float* __restrict__ x,      // [B, T, 1]
    const float* __restrict__ W_ih,   // [256, 1]
    const float* __restrict__ W_hh,   // [256, 64]
    const float* __restrict__ b_ih,   // [256]
    const float* __restrict__ b_hh,   // [256]
    const float* __restrict__ W_fc,   // [1, 64]
    const float* __restrict__ b_fc,   // [1]
    float* __restrict__ out,          // [B, 1]
    int B)
{
    __shared__ _Float16 Wf[2048 * 8];          // 32 KB, B-fragments, fragment-linear
    __shared__ _Float16 hbuf[WAVES * 1024];    // 16 KB, per-wave h A-fragments
    __shared__ float    wih_s[256];            // 1 KB (pre-scaled)
    __shared__ float    cb_s[256];             // 1 KB (pre-scaled b_ih + b_hh)

    const int tid = threadIdx.x;

    // ---- one-time staging: W_hh -> fp16 B-fragments, log2e pre-scaled ----
    #pragma unroll
    for (int s0 = 0; s0 < 2048; s0 += BLOCK) {
        const int s  = s0 + tid;
        const int ln = s & 63;
        const int kh = (s >> 6) & 1;
        const int n  = s >> 7;                             // N-tile 0..15, gate G = n>>2
        const float scl = ((n >> 2) == 2) ? (2.0f * L2E) : L2E;
        const int j  = n * 16 + (ln & 15);                 // gate row j'
        const int k0 = kh * 32 + ((ln >> 4) & 3) * 8;      // hidden k
        const float* src = W_hh + j * HDIM + k0;
        #pragma unroll
        for (int i = 0; i < 8; i++)
            Wf[s * 8 + i] = (_Float16)(src[i] * scl);
    }
    if (tid < 256) {
        const float scl = ((tid >> 6) == 2) ? (2.0f * L2E) : L2E;
        wih_s[tid] = W_ih[tid] * scl;
        cb_s[tid]  = (b_ih[tid] + b_hh[tid]) * scl;
    }
    __syncthreads();   // only barrier in the kernel

    const int lane = tid & 63;
    const int wave = tid >> 6;
    const int m    = lane & 15;    // C-layout column (gate-row local) / A row m
    const int q    = lane >> 4;    // quad
    const int eg0  = (blockIdx.x * WAVES + wave) * EPW;

    _Float16* hb = hbuf + wave * 1024;

    // x base pointers for this lane's 4 batch rows (hoisted; per-t load is imm offset)
    const float* xp[4];
    #pragma unroll
    for (int r = 0; r < 4; r++) {
        int e = eg0 + q * 4 + r;
        if (e >= B) e = B - 1;
        xp[r] = x + (long)e * TSTEPS;
    }

    float c[16];    // cell state, SCALED by 2*log2e; [gr*4+r] <-> (j=gr*16+m, e=q*4+r)
    float hv[16];   // last hidden state (unscaled), same indexing

    // broadcast gate coefficients (LDS, conflict-free); reused every timestep
    float wihv[4][4], cbv[4][4];   // [gr][G]
    #pragma unroll
    for (int gr = 0; gr < 4; gr++)
        #pragma unroll
        for (int G = 0; G < 4; G++) {
            wihv[gr][G] = wih_s[G * 64 + gr * 16 + m];
            cbv[gr][G]  = cb_s[G * 64 + gr * 16 + m];
        }

    // ================= t = 0 (peeled: c_prev = 0, no MFMA, no f-gate) ======
    {
        float xt[4];
        #pragma unroll
        for (int r = 0; r < 4; r++) xt[r] = xp[r][0];

        #pragma unroll
        for (int gr = 0; gr < 4; gr++) {
            #pragma unroll
            for (int r = 0; r < 4; r++) {
                const int u = gr * 4 + r;
                const float vi = fmaf(xt[r], wihv[gr][0], cbv[gr][0]);
                const float vg = fmaf(xt[r], wihv[gr][2], cbv[gr][2]);
                const float vo = fmaf(xt[r], wihv[gr][3], cbv[gr][3]);
                const float Ei = ex2_(-vi);
                const float Eg = ex2_(vg);
                const float Eo = ex2_(-vo);
                // cs = i*tanh(g), 2L2E-scaled
                const float cs = (2.0f * L2E) * (Eg - 1.0f) *
                                 rcp_((1.0f + Ei) * (Eg + 1.0f));
                c[u] = cs;
                const float Ec = ex2_(cs);
                const float hn = (Ec - 1.0f) * rcp_((1.0f + Eo) * (Ec + 1.0f));
                hv[u] = hn;
                const int lp = (q * 4 + r) + 16 * (2 * (gr & 1) + (m >> 3));
                hb[(gr >> 1) * 512 + lp * 8 + (m & 7)] = (_Float16)hn;
            }
        }
    }

    // ================= t = 1..4 (branch-free, fully unrolled) ==============
    #pragma unroll
    for (int t = 1; t < TSTEPS; t++) {
        float xt[4];
        #pragma unroll
        for (int r = 0; r < 4; r++) xt[r] = xp[r][t];

        // h A-fragments from previous timestep (same-wave LDS, no barrier needed)
        f16x8 hA0 = *(const f16x8*)(hb + lane * 8);          // kh = 0
        f16x8 hA1 = *(const f16x8*)(hb + 512 + lane * 8);    // kh = 1

        #pragma unroll
        for (int gr = 0; gr < 4; gr++) {       // j' chunk: j = gr*16 + m
            // C-init: bias + x*W_ih directly as the MFMA C operand
            f32x4 ag[4];
            #pragma unroll
            for (int G = 0; G < 4; G++)
                #pragma unroll
                for (int r = 0; r < 4; r++)
                    ag[G][r] = fmaf(xt[r], wihv[gr][G], cbv[gr][G]);

            #pragma unroll
            for (int G = 0; G < 4; G++) {
                const int n = G * 4 + gr;
                f16x8 w0 = *(const f16x8*)(Wf + (n * 2 + 0) * 512 + lane * 8);
                f16x8 w1 = *(const f16x8*)(Wf + (n * 2 + 1) * 512 + lane * 8);
                ag[G] = __builtin_amdgcn_mfma_f32_16x16x32_f16(hA0, w0, ag[G], 0, 0, 0);
                ag[G] = __builtin_amdgcn_mfma_f32_16x16x32_f16(hA1, w1, ag[G], 0, 0, 0);
            }

            #pragma unroll
            for (int r = 0; r < 4; r++) {
                const int u = gr * 4 + r;
                // 5 ex2 + 3 rcp, all short local chains
                const float Ei = ex2_(-ag[0][r]);
                const float Eg = ex2_(ag[2][r]);
                const float it = (2.0f * L2E) * (Eg - 1.0f) *
                                 rcp_((1.0f + Ei) * (Eg + 1.0f));
                const float Ef = ex2_(-ag[1][r]);
                const float sf = rcp_(1.0f + Ef);
                const float cs = fmaf(sf, c[u], it);      // scaled domain
                c[u] = cs;
                const float Eo = ex2_(-ag[3][r]);
                const float Ec = ex2_(cs);
                const float hn = (Ec - 1.0f) * rcp_((1.0f + Eo) * (Ec + 1.0f));
                hv[u] = hn;
                if (t < TSTEPS - 1) {
                    // scatter h (fp16) into next timestep's A-fragment slots
                    const int lp = (q * 4 + r) + 16 * (2 * (gr & 1) + (m >> 3));
                    hb[(gr >> 1) * 512 + lp * 8 + (m & 7)] = (_Float16)hn;
                }
            }
        }
    }

    // ---- FC epilogue: out[e] = sum_j h[j][e] * W_fc[j] + b_fc ----
    float wfc[4];
    #pragma unroll
    for (int n = 0; n < 4; n++) wfc[n] = W_fc[n * 16 + m];
    const float bfc = b_fc[0];

    #pragma unroll
    for (int r = 0; r < 4; r++) {
        float p = hv[r] * wfc[0];
        p = fmaf(hv[4 + r],  wfc[1], p);
        p = fmaf(hv[8 + r],  wfc[2], p);
        p = fmaf(hv[12 + r], wfc[3], p);
        p += __shfl_xor(p, 1, 64);
        p += __shfl_xor(p, 2, 64);
        p += __shfl_xor(p, 4, 64);
        p += __shfl_xor(p, 8, 64);
        if (m == 0) {
            const int e = eg0 + q * 4 + r;
            if (e < B) out[e] = p + bfc;
        }
    }
}

extern "C" void kernel_launch(void* const* d_in, const int* in_sizes, int n_in,
                              void* d_out, int out_size, void* d_ws, size_t ws_size,
                              hipStream_t stream) {
    const float* x    = (const float*)d_in[0];
    const float* W_ih = (const float*)d_in[1];
    const float* W_hh = (const float*)d_in[2];
    const float* b_ih = (const float*)d_in[3];
    const float* b_hh = (const float*)d_in[4];
    const float* W_fc = (const float*)d_in[5];
    const float* b_fc = (const float*)d_in[6];
    float* out = (float*)d_out;

    const int B = in_sizes[0] / TSTEPS;   // x is [B, T, 1]
    const int grid = (B + EPB - 1) / EPB;
    lstm_mfma_kernel<<<grid, BLOCK, 0, stream>>>(x, W_ih, W_hh, b_ih, b_hh,
                                                 W_fc, b_fc, out, B);
}

// Round 4
// 174.076 us; speedup vs baseline: 5.1205x; 2.3086x over previous
//
#include <hip/hip_runtime.h>

#define HDIM   64
#define TSTEPS 5
#define WAVES  8
#define BLOCK  (WAVES * 64)     // 512 threads
#define EPW    16               // batch per wave = MFMA M
#define EPB    (WAVES * EPW)    // 128 batch per block

typedef _Float16 f16x8 __attribute__((ext_vector_type(8)));
typedef float    f32x4 __attribute__((ext_vector_type(4)));

#define L2E 1.44269504088896340736f   // log2(e)

// Native 1-ulp ops (trans pipe, quarter rate -> minimize count)
__device__ __forceinline__ float rcp_(float x) { return __builtin_amdgcn_rcpf(x); }
__device__ __forceinline__ float ex2_(float x) { return __builtin_amdgcn_exp2f(x); }

// Gates as D[m=batch e][n=gate row j'] = A[e][k] * B[k][j'] + C(bias + x*W_ih)
// A = h^T (per-timestep, rebuilt), B = W_hh^T (staged once, PRE-SCALED by
// log2e for i/f/o columns and 2*log2e for g columns so activations use raw
// v_exp_f32 = 2^x with no multiply).
// 16x16x32 f16 layouts (verified, absmax 9.8e-4):
//   A-frag: lane holds A[m=lane&15][k = kh*32 + (lane>>4)*8 + i], i=0..7
//   B-frag: lane holds B[k = kh*32 + (lane>>4)*8 + i][n = ntile*16 + (lane&15)]
//   C/D:    lane holds D[m = (lane>>4)*4 + reg][n = ntile*16 + (lane&15)]
//
// Activation: LOCAL fusions only, each temp consumed within 2-3 ops:
//   it = i*tanh(g)*2L2E = 2L2E*(Eg-1) * rcp((1+Ei)*(Eg+1))   (1 rcp, was 2)
//   sf = rcp(1+Ef)
//   cs = fmaf(sf, c, it)          [c kept in 2L2E-scaled domain]
//   hn = o*tanh(c) = (Ec-1) * rcp((1+Eo)*(Ec+1))             (1 rcp, was 2)
// -> 5 ex2 + 3 rcp per hidden unit (round-0 had 5 ex2 + 5 rcp).
//
// LAUNCH BOUNDS HISTORY (do not regress):
//   (512,4) -> compiler caps VGPR at 64: round-0 code fit (60), but any
//              variant needing >64 spills to scratch (rounds 2/3: ~1.4 GB
//              HBM traffic, 3.5-8x slowdown). Empirical cap ~= 256/arg2
//              on this toolchain: (1024,8)->32, (512,4)->64.
//   (512,2) -> cap ~128. Real occupancy is LDS-bound anyway (51.2 KB/block
//              -> 3 blocks/CU = 6 waves/EU) for any VGPR count <= 85, so
//              loosening the bound costs nothing and removes the cliff.
//   NO register hoisting of wih/cb coeff arrays (round-3 mistake: +32
//   always-live regs); LDS broadcast reads per (t,gr) are cheap.
__global__ __launch_bounds__(BLOCK, 2) void lstm_mfma_kernel(
    const float* __restrict__ x,      // [B, T, 1]
    const float* __restrict__ W_ih,   // [256, 1]
    const float* __restrict__ W_hh,   // [256, 64]
    const float* __restrict__ b_ih,   // [256]
    const float* __restrict__ b_hh,   // [256]
    const float* __restrict__ W_fc,   // [1, 64]
    const float* __restrict__ b_fc,   // [1]
    float* __restrict__ out,          // [B, 1]
    int B)
{
    __shared__ _Float16 Wf[2048 * 8];          // 32 KB, B-fragments, fragment-linear
    __shared__ _Float16 hbuf[WAVES * 1024];    // 16 KB, per-wave h A-fragments
    __shared__ float    wih_s[256];            // 1 KB (pre-scaled)
    __shared__ float    cb_s[256];             // 1 KB (pre-scaled b_ih + b_hh)

    const int tid = threadIdx.x;

    // ---- one-time staging: W_hh -> fp16 B-fragments, log2e pre-scaled ----
    #pragma unroll
    for (int s0 = 0; s0 < 2048; s0 += BLOCK) {
        const int s  = s0 + tid;
        const int ln = s & 63;
        const int kh = (s >> 6) & 1;
        const int n  = s >> 7;                             // N-tile 0..15, gate G = n>>2
        const float scl = ((n >> 2) == 2) ? (2.0f * L2E) : L2E;
        const int j  = n * 16 + (ln & 15);                 // gate row j'
        const int k0 = kh * 32 + ((ln >> 4) & 3) * 8;      // hidden k
        const float* src = W_hh + j * HDIM + k0;
        #pragma unroll
        for (int i = 0; i < 8; i++)
            Wf[s * 8 + i] = (_Float16)(src[i] * scl);
    }
    if (tid < 256) {
        const float scl = ((tid >> 6) == 2) ? (2.0f * L2E) : L2E;
        wih_s[tid] = W_ih[tid] * scl;
        cb_s[tid]  = (b_ih[tid] + b_hh[tid]) * scl;
    }
    __syncthreads();   // only barrier in the kernel

    const int lane = tid & 63;
    const int wave = tid >> 6;
    const int m    = lane & 15;    // C-layout column (gate-row local) / A row m
    const int q    = lane >> 4;    // quad
    const int eg0  = (blockIdx.x * WAVES + wave) * EPW;

    _Float16* hb = hbuf + wave * 1024;

    // x base pointers for this lane's 4 batch rows (hoisted; per-t load is imm offset)
    const float* xp[4];
    #pragma unroll
    for (int r = 0; r < 4; r++) {
        int e = eg0 + q * 4 + r;
        if (e >= B) e = B - 1;
        xp[r] = x + (long)e * TSTEPS;
    }

    float c[16];    // cell state, SCALED by 2*log2e; [gr*4+r] <-> (j=gr*16+m, e=q*4+r)
    float hv[16];   // last hidden state (unscaled), same indexing

    for (int t = 0; t < TSTEPS; t++) {
        float xt[4];
        #pragma unroll
        for (int r = 0; r < 4; r++) xt[r] = xp[r][t];

        // h A-fragments from previous timestep (same-wave LDS, no barrier needed)
        f16x8 hA0, hA1;
        if (t > 0) {
            hA0 = *(const f16x8*)(hb + lane * 8);          // kh = 0
            hA1 = *(const f16x8*)(hb + 512 + lane * 8);    // kh = 1
        }

        #pragma unroll
        for (int gr = 0; gr < 4; gr++) {       // j' chunk: j = gr*16 + m
            // C-init: bias + x*W_ih directly as the MFMA C operand
            float wihv[4], cbv[4];
            #pragma unroll
            for (int G = 0; G < 4; G++) {
                wihv[G] = wih_s[G * 64 + gr * 16 + m];   // broadcast, conflict-free
                cbv[G]  = cb_s[G * 64 + gr * 16 + m];
            }
            f32x4 ag[4];
            #pragma unroll
            for (int G = 0; G < 4; G++)
                #pragma unroll
                for (int r = 0; r < 4; r++)
                    ag[G][r] = fmaf(xt[r], wihv[G], cbv[G]);

            if (t > 0) {
                #pragma unroll
                for (int G = 0; G < 4; G++) {
                    const int n = G * 4 + gr;
                    f16x8 w0 = *(const f16x8*)(Wf + (n * 2 + 0) * 512 + lane * 8);
                    f16x8 w1 = *(const f16x8*)(Wf + (n * 2 + 1) * 512 + lane * 8);
                    ag[G] = __builtin_amdgcn_mfma_f32_16x16x32_f16(hA0, w0, ag[G], 0, 0, 0);
                    ag[G] = __builtin_amdgcn_mfma_f32_16x16x32_f16(hA1, w1, ag[G], 0, 0, 0);
                }
            }

            #pragma unroll
            for (int r = 0; r < 4; r++) {
                const int u = gr * 4 + r;
                // 5 ex2 + 3 rcp, all short local chains
                const float Ei = ex2_(-ag[0][r]);
                const float Eg = ex2_(ag[2][r]);
                const float it = (2.0f * L2E) * (Eg - 1.0f) *
                                 rcp_((1.0f + Ei) * (Eg + 1.0f));
                const float Ef = ex2_(-ag[1][r]);
                const float sf = rcp_(1.0f + Ef);
                float cs = it;
                if (t > 0) cs = fmaf(sf, c[u], cs);
                c[u] = cs;                                    // scaled domain
                const float Eo = ex2_(-ag[3][r]);
                const float Ec = ex2_(cs);
                const float hn = (Ec - 1.0f) * rcp_((1.0f + Eo) * (Ec + 1.0f));
                hv[u] = hn;
                if (t < TSTEPS - 1) {
                    // scatter h (fp16) into next timestep's A-fragment slots
                    const int lp = (q * 4 + r) + 16 * (2 * (gr & 1) + (m >> 3));
                    hb[(gr >> 1) * 512 + lp * 8 + (m & 7)] = (_Float16)hn;
                }
            }
        }
    }

    // ---- FC epilogue: out[e] = sum_j h[j][e] * W_fc[j] + b_fc ----
    float wfc[4];
    #pragma unroll
    for (int n = 0; n < 4; n++) wfc[n] = W_fc[n * 16 + m];
    const float bfc = b_fc[0];

    #pragma unroll
    for (int r = 0; r < 4; r++) {
        float p = hv[r] * wfc[0];
        p = fmaf(hv[4 + r],  wfc[1], p);
        p = fmaf(hv[8 + r],  wfc[2], p);
        p = fmaf(hv[12 + r], wfc[3], p);
        p += __shfl_xor(p, 1, 64);
        p += __shfl_xor(p, 2, 64);
        p += __shfl_xor(p, 4, 64);
        p += __shfl_xor(p, 8, 64);
        if (m == 0) {
            const int e = eg0 + q * 4 + r;
            if (e < B) out[e] = p + bfc;
        }
    }
}

extern "C" void kernel_launch(void* const* d_in, const int* in_sizes, int n_in,
                              void* d_out, int out_size, void* d_ws, size_t ws_size,
                              hipStream_t stream) {
    const float* x    = (const float*)d_in[0];
    const float* W_ih = (const float*)d_in[1];
    const float* W_hh = (const float*)d_in[2];
    const float* b_ih = (const float*)d_in[3];
    const float* b_hh = (const float*)d_in[4];
    const float* W_fc = (const float*)d_in[5];
    const float* b_fc = (const float*)d_in[6];
    float* out = (float*)d_out;

    const int B = in_sizes[0] / TSTEPS;   // x is [B, T, 1]
    const int grid = (B + EPB - 1) / EPB;
    lstm_mfma_kernel<<<grid, BLOCK, 0, stream>>>(x, W_ih, W_hh, b_ih, b_hh,
                                                 W_fc, b_fc, out, B);
}